// Round 2
// baseline (291.078 us; speedup 1.0000x reference)
//
#include <hip/hip_runtime.h>
#include <math.h>

// B=32, HID=4096, NH=32, NKV=8, HS=128, BS=16, MAXS=2048, groups=4

// ---------------------------------------------------------------------------
// Split-K f32 GEMM: out[b][n] += x[b][:] . w[n][:] over K-chunk of kcnt.
// BM=32, BN=256, BK=32. 256 threads, 32 accumulators/thread.
// ---------------------------------------------------------------------------
__device__ __forceinline__ void gemm_body(
    const float* __restrict__ x, const float* __restrict__ w,
    float* __restrict__ dst, int dstride, int kbase, int kcnt)
{
    __shared__ float xs[32][36];
    __shared__ float wsm[32][257];   // [k][n]
    int t = threadIdx.x;
    float acc[4][8];
#pragma unroll
    for (int i = 0; i < 4; ++i)
#pragma unroll
        for (int j = 0; j < 8; ++j) acc[i][j] = 0.f;

    int nsub = t & 31, bsub = t >> 5;

    for (int kt = 0; kt < kcnt; kt += 32) {
        int k0 = kbase + kt;
        {
            int b = t >> 3, k4 = (t & 7) << 2;
            float4 xv = *(const float4*)(x + (size_t)b * 4096 + k0 + k4);
            *(float4*)&xs[b][k4] = xv;
        }
        {
            int k4 = (t & 7) << 2;
            int nl0 = t >> 3;
#pragma unroll
            for (int i = 0; i < 8; ++i) {
                int nl = nl0 + (i << 5);
                float4 wv = *(const float4*)(w + (size_t)nl * 4096 + k0 + k4);
                wsm[k4 + 0][nl] = wv.x;
                wsm[k4 + 1][nl] = wv.y;
                wsm[k4 + 2][nl] = wv.z;
                wsm[k4 + 3][nl] = wv.w;
            }
        }
        __syncthreads();
#pragma unroll
        for (int k = 0; k < 32; ++k) {
            float xv[4], wv[8];
#pragma unroll
            for (int j = 0; j < 4; ++j) xv[j] = xs[bsub * 4 + j][k];
#pragma unroll
            for (int j = 0; j < 8; ++j) wv[j] = wsm[k][nsub + (j << 5)];
#pragma unroll
            for (int jb = 0; jb < 4; ++jb)
#pragma unroll
                for (int jn = 0; jn < 8; ++jn)
                    acc[jb][jn] = fmaf(xv[jb], wv[jn], acc[jb][jn]);
        }
        __syncthreads();
    }
#pragma unroll
    for (int jb = 0; jb < 4; ++jb) {
        int b = bsub * 4 + jb;
#pragma unroll
        for (int jn = 0; jn < 8; ++jn)
            atomicAdd(dst + (size_t)b * dstride + nsub + (jn << 5), acc[jb][jn]);
    }
}

// grid = 24 tiles * 32 splits
__global__ __launch_bounds__(256) void qkv_gemm(
    const float* __restrict__ x, const float* __restrict__ wq,
    const float* __restrict__ wk, const float* __restrict__ wv,
    float* __restrict__ qb, float* __restrict__ knb, float* __restrict__ vnb)
{
    int split = blockIdx.x & 31;
    int tile  = blockIdx.x >> 5;
    const float* w; float* dst; int dstride;
    if (tile < 16)      { w = wq + (size_t)tile * 256 * 4096;        dst = qb  + tile * 256;        dstride = 4096; }
    else if (tile < 20) { w = wk + (size_t)(tile - 16) * 256 * 4096; dst = knb + (tile - 16) * 256; dstride = 1024; }
    else                { w = wv + (size_t)(tile - 20) * 256 * 4096; dst = vnb + (tile - 20) * 256; dstride = 1024; }
    gemm_body(x, w, dst, dstride, split * 128, 128);
}

// grid = 16 tiles * 32 splits
__global__ __launch_bounds__(256) void wo_gemm(
    const float* __restrict__ attn, const float* __restrict__ wo,
    float* __restrict__ out)
{
    int split = blockIdx.x & 31;
    int tile  = blockIdx.x >> 5;
    gemm_body(attn, wo + (size_t)tile * 256 * 4096, out + tile * 256, 4096, split * 128, 128);
}

// ---------------------------------------------------------------------------
// RoPE in-place on q (32 heads) and k_new (8 heads). grid = 32*40, block = 64.
// ---------------------------------------------------------------------------
__global__ void rope_kernel(float* __restrict__ qb, float* __restrict__ knb,
                            const int* __restrict__ lens)
{
    int bid = blockIdx.x;
    int b = bid / 40, r = bid % 40;
    float* row = (r < 32) ? (qb + (size_t)b * 4096 + r * 128)
                          : (knb + (size_t)b * 1024 + (r - 32) * 128);
    int d = threadIdx.x;
    float pos = (float)(lens[b] - 1);
    float inv = exp2f(-(float)d * 0.207620505930460f);  // 10000^(-d/64)
    float fr = pos * inv;
    float s, c;
    sincosf(fr, &s, &c);
    float x1 = row[d], x2 = row[d + 64];
    row[d]      = x1 * c - x2 * s;
    row[d + 64] = x2 * c + x1 * s;
}

// ---------------------------------------------------------------------------
// Flash-decode attention. grid = 32*8*8 chunks of 256 positions, block = 256.
// Pipeline per 64-tile: prefetch K(t+1)->regs | scores(t) from swizzled K-LDS
// (wave=group) | barrier | PV(t) from GLOBAL V (wave=row-block, all 4 groups)
// + ds_write K(t+1) | barrier.  Slot table precomputed in LDS.
// ---------------------------------------------------------------------------
__global__ __launch_bounds__(256, 4) void attn_kernel(
    const float* __restrict__ kc, const float* __restrict__ vc,
    const float* __restrict__ qb, const float* __restrict__ knb,
    const float* __restrict__ vnb,
    const int* __restrict__ btab, const int* __restrict__ lens,
    float* __restrict__ part)
{
    int bid = blockIdx.x;
    int c = bid & 7, h = (bid >> 3) & 7, b = bid >> 6;
    int len = lens[b];
    int p0 = c << 8;
    if (p0 >= len) return;
    int pend = min(len - p0, 256);
    int nt = (pend + 63) >> 6;
    int last = len - 1;

    __shared__ float ks[64][128];   // 32 KB, f4-col XOR-swizzled
    __shared__ float qs[4][128];
    __shared__ float ps[4][64];
    __shared__ int   ss[256];       // slot table; -1 => new k/v row
    __shared__ float corrs[4];

    int t = threadIdx.x;
    int wave = t >> 6, lane = t & 63;

    {   // slot table for the whole chunk
        int p = p0 + t;
        ss[t] = (p == last) ? -1 : (btab[b * 128 + (p >> 4)] * 16 + (p & 15));
    }
    if (t < 128) {
        int g = t >> 5, d4 = (t & 31) << 2;
        *(float4*)&qs[g][d4] =
            *(const float4*)(qb + (size_t)b * 4096 + (size_t)(h * 4 + g) * 128 + d4);
    }
    __syncthreads();

    int pr_row = t >> 2;          // 0..63
    int pr_q   = t & 3;           // 128B quarter of the row
    int r7 = pr_row & 7;
    const float* knew = knb + ((size_t)b * 8 + h) * 128;
    const float* vnew = vnb + ((size_t)b * 8 + h) * 128;

    float4 kreg[8];
    {   // prologue: tile 0 -> regs -> LDS (swizzled)
        int sl = ss[pr_row];
        const float* src = (sl < 0) ? knew : (kc + (size_t)sl * 1024 + h * 128);
        src += pr_q * 32;
#pragma unroll
        for (int j = 0; j < 8; ++j) kreg[j] = *(const float4*)(src + j * 4);
#pragma unroll
        for (int j = 0; j < 8; ++j) {
            int c4 = (pr_q << 3) + j;
            *(float4*)&ks[pr_row][(c4 ^ r7) << 2] = kreg[j];
        }
    }
    __syncthreads();

    float m = -INFINITY, lsum = 0.f;
    float o[4][2];
#pragma unroll
    for (int g = 0; g < 4; ++g) { o[g][0] = 0.f; o[g][1] = 0.f; }

    const float scale = 0.08838834764831845f;
    int xm = lane & 7;
    int d0 = lane << 1;

    for (int tt = 0; tt < nt; ++tt) {
        int tlen = min(pend - (tt << 6), 64);
        // ---- A: prefetch K(t+1) into regs ----
        if (tt + 1 < nt) {
            int sl = ss[((tt + 1) << 6) + pr_row];
            const float* src = (sl < 0) ? knew : (kc + (size_t)sl * 1024 + h * 128);
            src += pr_q * 32;
#pragma unroll
            for (int j = 0; j < 8; ++j) kreg[j] = *(const float4*)(src + j * 4);
        }
        // ---- B: scores(t), wave = GQA group ----
        {
            float ax = 0.f, ay = 0.f, az = 0.f, aw = 0.f;
#pragma unroll
            for (int cc = 0; cc < 32; ++cc) {
                float4 kv = *(float4*)&ks[lane][(cc ^ xm) << 2];
                float4 qv = *(const float4*)&qs[wave][cc << 2];
                ax = fmaf(kv.x, qv.x, ax);
                ay = fmaf(kv.y, qv.y, ay);
                az = fmaf(kv.z, qv.z, az);
                aw = fmaf(kv.w, qv.w, aw);
            }
            float s = (lane < tlen) ? (ax + ay + az + aw) * scale : -INFINITY;
            float smax = s;
#pragma unroll
            for (int off = 32; off; off >>= 1) smax = fmaxf(smax, __shfl_xor(smax, off, 64));
            float mnew = fmaxf(m, smax);
            float corr = __expf(m - mnew);
            float pexp = (lane < tlen) ? __expf(s - mnew) : 0.f;
            float psum = pexp;
#pragma unroll
            for (int off = 32; off; off >>= 1) psum += __shfl_xor(psum, off, 64);
            lsum = lsum * corr + psum;
            m = mnew;
            ps[wave][lane] = pexp;
            if (lane == 0) corrs[wave] = corr;
        }
        __syncthreads();   // C: ps/corr visible; everyone done reading ks(t)
        // ---- D: PV(t), wave = row block (16 rows), all 4 groups ----
        {
#pragma unroll
            for (int g = 0; g < 4; ++g) { float cg = corrs[g]; o[g][0] *= cg; o[g][1] *= cg; }
            int rp0 = wave << 4;
            int ibase = (tt << 6) + rp0;
#pragma unroll
            for (int i4 = 0; i4 < 16; i4 += 4) {
                int4 s4 = *(const int4*)&ss[ibase + i4];
                const float* v0 = (s4.x < 0) ? vnew : (vc + (size_t)s4.x * 1024 + h * 128);
                const float* v1 = (s4.y < 0) ? vnew : (vc + (size_t)s4.y * 1024 + h * 128);
                const float* v2 = (s4.z < 0) ? vnew : (vc + (size_t)s4.z * 1024 + h * 128);
                const float* v3 = (s4.w < 0) ? vnew : (vc + (size_t)s4.w * 1024 + h * 128);
                float2 a0 = *(const float2*)(v0 + d0);
                float2 a1 = *(const float2*)(v1 + d0);
                float2 a2 = *(const float2*)(v2 + d0);
                float2 a3 = *(const float2*)(v3 + d0);
                float4 w0 = *(const float4*)&ps[0][rp0 + i4];
                float4 w1 = *(const float4*)&ps[1][rp0 + i4];
                float4 w2 = *(const float4*)&ps[2][rp0 + i4];
                float4 w3 = *(const float4*)&ps[3][rp0 + i4];
                o[0][0] = fmaf(w0.x, a0.x, o[0][0]); o[0][1] = fmaf(w0.x, a0.y, o[0][1]);
                o[0][0] = fmaf(w0.y, a1.x, o[0][0]); o[0][1] = fmaf(w0.y, a1.y, o[0][1]);
                o[0][0] = fmaf(w0.z, a2.x, o[0][0]); o[0][1] = fmaf(w0.z, a2.y, o[0][1]);
                o[0][0] = fmaf(w0.w, a3.x, o[0][0]); o[0][1] = fmaf(w0.w, a3.y, o[0][1]);
                o[1][0] = fmaf(w1.x, a0.x, o[1][0]); o[1][1] = fmaf(w1.x, a0.y, o[1][1]);
                o[1][0] = fmaf(w1.y, a1.x, o[1][0]); o[1][1] = fmaf(w1.y, a1.y, o[1][1]);
                o[1][0] = fmaf(w1.z, a2.x, o[1][0]); o[1][1] = fmaf(w1.z, a2.y, o[1][1]);
                o[1][0] = fmaf(w1.w, a3.x, o[1][0]); o[1][1] = fmaf(w1.w, a3.y, o[1][1]);
                o[2][0] = fmaf(w2.x, a0.x, o[2][0]); o[2][1] = fmaf(w2.x, a0.y, o[2][1]);
                o[2][0] = fmaf(w2.y, a1.x, o[2][0]); o[2][1] = fmaf(w2.y, a1.y, o[2][1]);
                o[2][0] = fmaf(w2.z, a2.x, o[2][0]); o[2][1] = fmaf(w2.z, a2.y, o[2][1]);
                o[2][0] = fmaf(w2.w, a3.x, o[2][0]); o[2][1] = fmaf(w2.w, a3.y, o[2][1]);
                o[3][0] = fmaf(w3.x, a0.x, o[3][0]); o[3][1] = fmaf(w3.x, a0.y, o[3][1]);
                o[3][0] = fmaf(w3.y, a1.x, o[3][0]); o[3][1] = fmaf(w3.y, a1.y, o[3][1]);
                o[3][0] = fmaf(w3.z, a2.x, o[3][0]); o[3][1] = fmaf(w3.z, a2.y, o[3][1]);
                o[3][0] = fmaf(w3.w, a3.x, o[3][0]); o[3][1] = fmaf(w3.w, a3.y, o[3][1]);
            }
        }
        // ---- E: commit prefetched K(t+1) to LDS (swizzled) ----
        if (tt + 1 < nt) {
#pragma unroll
            for (int j = 0; j < 8; ++j) {
                int c4 = (pr_q << 3) + j;
                *(float4*)&ks[pr_row][(c4 ^ r7) << 2] = kreg[j];
            }
        }
        __syncthreads();   // F
    }

    // epilogue: cross-wave O reduction (overlay scratch on ks)
    float* oacc = (float*)ks;   // [wave][g][128]
#pragma unroll
    for (int g = 0; g < 4; ++g) {
        oacc[(wave * 4 + g) * 128 + d0]     = o[g][0];
        oacc[(wave * 4 + g) * 128 + d0 + 1] = o[g][1];
    }
    float* pgbase = part + (size_t)(((b * 8 + h) * 8 + c) * 4) * 130;
    if (lane == 0) { pgbase[wave * 130] = m; pgbase[wave * 130 + 1] = lsum; }
    __syncthreads();
    for (int e = t; e < 512; e += 256) {
        int g = e >> 7, d = e & 127;
        float v = oacc[(0 + g) * 128 + d] + oacc[(4 + g) * 128 + d]
                + oacc[(8 + g) * 128 + d] + oacc[(12 + g) * 128 + d];
        pgbase[g * 130 + 2 + d] = v;
    }
}

// grid = 256 (b*8+h), block = 256 (4 groups x 64 lanes)
__global__ __launch_bounds__(256) void combine_kernel(
    const float* __restrict__ part, const int* __restrict__ lens,
    float* __restrict__ attn)
{
    int b = blockIdx.x >> 3, h = blockIdx.x & 7;
    int t = threadIdx.x;
    int g = t >> 6, lane = t & 63;
    int len = lens[b];
    int nch = (len + 255) >> 8;
    size_t base = ((size_t)(b * 8 + h) * 32 + g) * 130;
    float M = -INFINITY;
    for (int cc = 0; cc < nch; ++cc)
        M = fmaxf(M, part[base + (size_t)cc * 520]);
    float denom = 0.f, a0 = 0.f, a1 = 0.f;
    for (int cc = 0; cc < nch; ++cc) {
        const float* pg = part + base + (size_t)cc * 520;
        float w = __expf(pg[0] - M);
        denom += w * pg[1];
        a0 += w * pg[2 + (lane << 1)];
        a1 += w * pg[3 + (lane << 1)];
    }
    float inv = 1.f / denom;
    float* dst = attn + (size_t)b * 4096 + (size_t)(h * 4 + g) * 128 + (lane << 1);
    dst[0] = a0 * inv;
    dst[1] = a1 * inv;
}

// ---------------------------------------------------------------------------
// Workspace (floats): qb[32][4096] @0, knb[32*1024] @131072, vnb @163840,
// attn[32][4096] @196608, part[32*8*8*4*130] @327680  (~5.6 MB)
// ---------------------------------------------------------------------------
extern "C" void kernel_launch(void* const* d_in, const int* in_sizes, int n_in,
                              void* d_out, int out_size, void* d_ws, size_t ws_size,
                              hipStream_t stream)
{
    const float* x   = (const float*)d_in[0];
    const float* wq  = (const float*)d_in[1];
    const float* wk  = (const float*)d_in[2];
    const float* wv  = (const float*)d_in[3];
    const float* wo  = (const float*)d_in[4];
    const float* kc  = (const float*)d_in[5];
    const float* vc  = (const float*)d_in[6];
    const int* btab  = (const int*)d_in[8];
    const int* lens  = (const int*)d_in[10];

    float* qb   = (float*)d_ws;
    float* knb  = qb  + 32 * 4096;
    float* vnb  = knb + 32 * 1024;
    float* attn = vnb + 32 * 1024;
    float* part = attn + 32 * 4096;
    float* outp = (float*)d_out;

    hipMemsetAsync(d_ws, 0, (size_t)(32 * 4096 + 2 * 32 * 1024) * sizeof(float), stream);
    hipMemsetAsync(d_out, 0, (size_t)32 * 4096 * sizeof(float), stream);

    qkv_gemm<<<24 * 32, 256, 0, stream>>>(x, wq, wk, wv, qb, knb, vnb);
    rope_kernel<<<32 * 40, 64, 0, stream>>>(qb, knb, lens);
    attn_kernel<<<2048, 256, 0, stream>>>(kc, vc, qb, knb, vnb, btab, lens, part);
    combine_kernel<<<256, 256, 0, stream>>>(part, lens, attn);
    wo_gemm<<<16 * 32, 256, 0, stream>>>(attn, wo, outp);
}

// Round 3
// 254.761 us; speedup vs baseline: 1.1426x; 1.1426x over previous
//
#include <hip/hip_runtime.h>
#include <math.h>

// B=32, HID=4096, NH=32, NKV=8, HS=128, BS=16, MAXS=2048, groups=4

// ---------------------------------------------------------------------------
// Split-K f32 GEMM: out[b][n] += x[b][:] . w[n][:] over K-chunk of kcnt.
// BM=32, BN=256, BK=32. 256 threads, 32 accumulators/thread.
// ---------------------------------------------------------------------------
__device__ __forceinline__ void gemm_body(
    const float* __restrict__ x, const float* __restrict__ w,
    float* __restrict__ dst, int dstride, int kbase, int kcnt)
{
    __shared__ float xs[32][36];
    __shared__ float wsm[32][257];   // [k][n]
    int t = threadIdx.x;
    float acc[4][8];
#pragma unroll
    for (int i = 0; i < 4; ++i)
#pragma unroll
        for (int j = 0; j < 8; ++j) acc[i][j] = 0.f;

    int nsub = t & 31, bsub = t >> 5;

    for (int kt = 0; kt < kcnt; kt += 32) {
        int k0 = kbase + kt;
        {
            int b = t >> 3, k4 = (t & 7) << 2;
            float4 xv = *(const float4*)(x + (size_t)b * 4096 + k0 + k4);
            *(float4*)&xs[b][k4] = xv;
        }
        {
            int k4 = (t & 7) << 2;
            int nl0 = t >> 3;
#pragma unroll
            for (int i = 0; i < 8; ++i) {
                int nl = nl0 + (i << 5);
                float4 wv = *(const float4*)(w + (size_t)nl * 4096 + k0 + k4);
                wsm[k4 + 0][nl] = wv.x;
                wsm[k4 + 1][nl] = wv.y;
                wsm[k4 + 2][nl] = wv.z;
                wsm[k4 + 3][nl] = wv.w;
            }
        }
        __syncthreads();
#pragma unroll
        for (int k = 0; k < 32; ++k) {
            float xv[4], wv[8];
#pragma unroll
            for (int j = 0; j < 4; ++j) xv[j] = xs[bsub * 4 + j][k];
#pragma unroll
            for (int j = 0; j < 8; ++j) wv[j] = wsm[k][nsub + (j << 5)];
#pragma unroll
            for (int jb = 0; jb < 4; ++jb)
#pragma unroll
                for (int jn = 0; jn < 8; ++jn)
                    acc[jb][jn] = fmaf(xv[jb], wv[jn], acc[jb][jn]);
        }
        __syncthreads();
    }
#pragma unroll
    for (int jb = 0; jb < 4; ++jb) {
        int b = bsub * 4 + jb;
#pragma unroll
        for (int jn = 0; jn < 8; ++jn)
            atomicAdd(dst + (size_t)b * dstride + nsub + (jn << 5), acc[jb][jn]);
    }
}

// grid = 24 tiles * 16 splits
__global__ __launch_bounds__(256) void qkv_gemm(
    const float* __restrict__ x, const float* __restrict__ wq,
    const float* __restrict__ wk, const float* __restrict__ wv,
    float* __restrict__ qb, float* __restrict__ knb, float* __restrict__ vnb)
{
    int split = blockIdx.x & 15;
    int tile  = blockIdx.x >> 4;
    const float* w; float* dst; int dstride;
    if (tile < 16)      { w = wq + (size_t)tile * 256 * 4096;        dst = qb  + tile * 256;        dstride = 4096; }
    else if (tile < 20) { w = wk + (size_t)(tile - 16) * 256 * 4096; dst = knb + (tile - 16) * 256; dstride = 1024; }
    else                { w = wv + (size_t)(tile - 20) * 256 * 4096; dst = vnb + (tile - 20) * 256; dstride = 1024; }
    gemm_body(x, w, dst, dstride, split * 256, 256);
}

// grid = 16 tiles * 16 splits
__global__ __launch_bounds__(256) void wo_gemm(
    const float* __restrict__ attn, const float* __restrict__ wo,
    float* __restrict__ out)
{
    int split = blockIdx.x & 15;
    int tile  = blockIdx.x >> 4;
    gemm_body(attn, wo + (size_t)tile * 256 * 4096, out + tile * 256, 4096, split * 256, 256);
}

// ---------------------------------------------------------------------------
// RoPE in-place on q (32 heads) and k_new (8 heads). grid = 32*40, block = 64.
// ---------------------------------------------------------------------------
__global__ void rope_kernel(float* __restrict__ qb, float* __restrict__ knb,
                            const int* __restrict__ lens)
{
    int bid = blockIdx.x;
    int b = bid / 40, r = bid % 40;
    float* row = (r < 32) ? (qb + (size_t)b * 4096 + r * 128)
                          : (knb + (size_t)b * 1024 + (r - 32) * 128);
    int d = threadIdx.x;
    float pos = (float)(lens[b] - 1);
    float inv = exp2f(-(float)d * 0.207620505930460f);  // 10000^(-d/64)
    float fr = pos * inv;
    float s, c;
    sincosf(fr, &s, &c);
    float x1 = row[d], x2 = row[d + 64];
    row[d]      = x1 * c - x2 * s;
    row[d + 64] = x2 * c + x1 * s;
}

// ---------------------------------------------------------------------------
// Flash-decode attention. grid = 32*8*8 chunks of 256 positions, block = 256.
// Per 64-tile: A: prefetch V(t)->vreg (16xf2) and K(t+1)->kreg (8xf4);
// B: scores(t) from swizzled K-LDS (wave=group) -- covers both load latencies;
// C: barrier; D: PV(t) pure-register FMA; E: commit K(t+1) to LDS; F: barrier.
// V never touches LDS. Slot table in LDS. No min-occupancy clause -> no spill.
// ---------------------------------------------------------------------------
__global__ __launch_bounds__(256, 2) void attn_kernel(
    const float* __restrict__ kc, const float* __restrict__ vc,
    const float* __restrict__ qb, const float* __restrict__ knb,
    const float* __restrict__ vnb,
    const int* __restrict__ btab, const int* __restrict__ lens,
    float* __restrict__ part)
{
    int bid = blockIdx.x;
    int c = bid & 7, h = (bid >> 3) & 7, b = bid >> 6;
    int len = lens[b];
    int p0 = c << 8;
    if (p0 >= len) return;
    int pend = min(len - p0, 256);
    int nt = (pend + 63) >> 6;
    int last = len - 1;

    __shared__ float ks[64][128];   // 32 KB, f4-col XOR-swizzled
    __shared__ float qs[4][128];
    __shared__ float ps[4][64];
    __shared__ int   ss[256];       // slot table; -1 => new k/v row
    __shared__ float corrs[4];

    int t = threadIdx.x;
    int wave = t >> 6, lane = t & 63;

    {   // slot table for the whole chunk
        int p = p0 + t;
        ss[t] = (p == last) ? -1 : (btab[b * 128 + (p >> 4)] * 16 + (p & 15));
    }
    if (t < 128) {
        int g = t >> 5, d4 = (t & 31) << 2;
        *(float4*)&qs[g][d4] =
            *(const float4*)(qb + (size_t)b * 4096 + (size_t)(h * 4 + g) * 128 + d4);
    }
    __syncthreads();

    int pr_row = t >> 2;          // 0..63
    int pr_q   = t & 3;           // 128B quarter of the row
    int r7 = pr_row & 7;
    const float* knew = knb + ((size_t)b * 8 + h) * 128;
    const float* vnew = vnb + ((size_t)b * 8 + h) * 128;

    float4 kreg[8];
    {   // prologue: K tile 0 -> regs -> LDS (swizzled)
        int sl = ss[pr_row];
        const float* src = (sl < 0) ? knew : (kc + (size_t)sl * 1024 + h * 128);
        src += pr_q * 32;
#pragma unroll
        for (int j = 0; j < 8; ++j) kreg[j] = *(const float4*)(src + j * 4);
#pragma unroll
        for (int j = 0; j < 8; ++j) {
            int c4 = (pr_q << 3) + j;
            *(float4*)&ks[pr_row][(c4 ^ r7) << 2] = kreg[j];
        }
    }
    __syncthreads();

    float m = -INFINITY, lsum = 0.f;
    float o[4][2];
#pragma unroll
    for (int g = 0; g < 4; ++g) { o[g][0] = 0.f; o[g][1] = 0.f; }

    const float scale = 0.08838834764831845f;
    int xm = lane & 7;
    int d0 = lane << 1;
    int rp0 = wave << 4;

    for (int tt = 0; tt < nt; ++tt) {
        int tlen = min(pend - (tt << 6), 64);
        // ---- A1: prefetch V(t) into regs (rows rp0..rp0+15, coalesced) ----
        float2 vreg[16];
        {
            int ibase = (tt << 6) + rp0;
#pragma unroll
            for (int i = 0; i < 16; ++i) {
                int sl = ss[ibase + i];
                const float* src = (sl < 0) ? vnew : (vc + (size_t)sl * 1024 + h * 128);
                vreg[i] = *(const float2*)(src + d0);
            }
        }
        // ---- A2: prefetch K(t+1) into regs ----
        if (tt + 1 < nt) {
            int sl = ss[((tt + 1) << 6) + pr_row];
            const float* src = (sl < 0) ? knew : (kc + (size_t)sl * 1024 + h * 128);
            src += pr_q * 32;
#pragma unroll
            for (int j = 0; j < 8; ++j) kreg[j] = *(const float4*)(src + j * 4);
        }
        // ---- B: scores(t), wave = GQA group ----
        {
            float ax = 0.f, ay = 0.f, az = 0.f, aw = 0.f;
#pragma unroll
            for (int cc = 0; cc < 32; ++cc) {
                float4 kv = *(float4*)&ks[lane][(cc ^ xm) << 2];
                float4 qv = *(const float4*)&qs[wave][cc << 2];
                ax = fmaf(kv.x, qv.x, ax);
                ay = fmaf(kv.y, qv.y, ay);
                az = fmaf(kv.z, qv.z, az);
                aw = fmaf(kv.w, qv.w, aw);
            }
            float s = (lane < tlen) ? (ax + ay + az + aw) * scale : -INFINITY;
            float smax = s;
#pragma unroll
            for (int off = 32; off; off >>= 1) smax = fmaxf(smax, __shfl_xor(smax, off, 64));
            float mnew = fmaxf(m, smax);
            float corr = __expf(m - mnew);
            float pexp = (lane < tlen) ? __expf(s - mnew) : 0.f;
            float psum = pexp;
#pragma unroll
            for (int off = 32; off; off >>= 1) psum += __shfl_xor(psum, off, 64);
            lsum = lsum * corr + psum;
            m = mnew;
            ps[wave][lane] = pexp;
            if (lane == 0) corrs[wave] = corr;
        }
        __syncthreads();   // C
        // ---- D: PV(t) from registers; wave covers rows rp0..rp0+15, all 4 g ----
        {
#pragma unroll
            for (int g = 0; g < 4; ++g) { float cg = corrs[g]; o[g][0] *= cg; o[g][1] *= cg; }
#pragma unroll
            for (int i4 = 0; i4 < 16; i4 += 4) {
                float4 w0 = *(const float4*)&ps[0][rp0 + i4];
                float4 w1 = *(const float4*)&ps[1][rp0 + i4];
                float4 w2 = *(const float4*)&ps[2][rp0 + i4];
                float4 w3 = *(const float4*)&ps[3][rp0 + i4];
                float2 a0 = vreg[i4], a1 = vreg[i4 + 1], a2 = vreg[i4 + 2], a3 = vreg[i4 + 3];
                o[0][0] = fmaf(w0.x, a0.x, o[0][0]); o[0][1] = fmaf(w0.x, a0.y, o[0][1]);
                o[0][0] = fmaf(w0.y, a1.x, o[0][0]); o[0][1] = fmaf(w0.y, a1.y, o[0][1]);
                o[0][0] = fmaf(w0.z, a2.x, o[0][0]); o[0][1] = fmaf(w0.z, a2.y, o[0][1]);
                o[0][0] = fmaf(w0.w, a3.x, o[0][0]); o[0][1] = fmaf(w0.w, a3.y, o[0][1]);
                o[1][0] = fmaf(w1.x, a0.x, o[1][0]); o[1][1] = fmaf(w1.x, a0.y, o[1][1]);
                o[1][0] = fmaf(w1.y, a1.x, o[1][0]); o[1][1] = fmaf(w1.y, a1.y, o[1][1]);
                o[1][0] = fmaf(w1.z, a2.x, o[1][0]); o[1][1] = fmaf(w1.z, a2.y, o[1][1]);
                o[1][0] = fmaf(w1.w, a3.x, o[1][0]); o[1][1] = fmaf(w1.w, a3.y, o[1][1]);
                o[2][0] = fmaf(w2.x, a0.x, o[2][0]); o[2][1] = fmaf(w2.x, a0.y, o[2][1]);
                o[2][0] = fmaf(w2.y, a1.x, o[2][0]); o[2][1] = fmaf(w2.y, a1.y, o[2][1]);
                o[2][0] = fmaf(w2.z, a2.x, o[2][0]); o[2][1] = fmaf(w2.z, a2.y, o[2][1]);
                o[2][0] = fmaf(w2.w, a3.x, o[2][0]); o[2][1] = fmaf(w2.w, a3.y, o[2][1]);
                o[3][0] = fmaf(w3.x, a0.x, o[3][0]); o[3][1] = fmaf(w3.x, a0.y, o[3][1]);
                o[3][0] = fmaf(w3.y, a1.x, o[3][0]); o[3][1] = fmaf(w3.y, a1.y, o[3][1]);
                o[3][0] = fmaf(w3.z, a2.x, o[3][0]); o[3][1] = fmaf(w3.z, a2.y, o[3][1]);
                o[3][0] = fmaf(w3.w, a3.x, o[3][0]); o[3][1] = fmaf(w3.w, a3.y, o[3][1]);
            }
        }
        // ---- E: commit prefetched K(t+1) to LDS (swizzled) ----
        if (tt + 1 < nt) {
#pragma unroll
            for (int j = 0; j < 8; ++j) {
                int c4 = (pr_q << 3) + j;
                *(float4*)&ks[pr_row][(c4 ^ r7) << 2] = kreg[j];
            }
        }
        __syncthreads();   // F
    }

    // epilogue: cross-wave O reduction (overlay scratch on ks)
    float* oacc = (float*)ks;   // [wave][g][128]
#pragma unroll
    for (int g = 0; g < 4; ++g) {
        oacc[(wave * 4 + g) * 128 + d0]     = o[g][0];
        oacc[(wave * 4 + g) * 128 + d0 + 1] = o[g][1];
    }
    float* pgbase = part + (size_t)(((b * 8 + h) * 8 + c) * 4) * 130;
    if (lane == 0) { pgbase[wave * 130] = m; pgbase[wave * 130 + 1] = lsum; }
    __syncthreads();
    for (int e = t; e < 512; e += 256) {
        int g = e >> 7, d = e & 127;
        float v = oacc[(0 + g) * 128 + d] + oacc[(4 + g) * 128 + d]
                + oacc[(8 + g) * 128 + d] + oacc[(12 + g) * 128 + d];
        pgbase[g * 130 + 2 + d] = v;
    }
}

// grid = 256 (b*8+h), block = 256 (4 groups x 64 lanes)
__global__ __launch_bounds__(256) void combine_kernel(
    const float* __restrict__ part, const int* __restrict__ lens,
    float* __restrict__ attn)
{
    int b = blockIdx.x >> 3, h = blockIdx.x & 7;
    int t = threadIdx.x;
    int g = t >> 6, lane = t & 63;
    int len = lens[b];
    int nch = (len + 255) >> 8;
    size_t base = ((size_t)(b * 8 + h) * 32 + g) * 130;
    float M = -INFINITY;
    for (int cc = 0; cc < nch; ++cc)
        M = fmaxf(M, part[base + (size_t)cc * 520]);
    float denom = 0.f, a0 = 0.f, a1 = 0.f;
    for (int cc = 0; cc < nch; ++cc) {
        const float* pg = part + base + (size_t)cc * 520;
        float w = __expf(pg[0] - M);
        denom += w * pg[1];
        a0 += w * pg[2 + (lane << 1)];
        a1 += w * pg[3 + (lane << 1)];
    }
    float inv = 1.f / denom;
    float* dst = attn + (size_t)b * 4096 + (size_t)(h * 4 + g) * 128 + (lane << 1);
    dst[0] = a0 * inv;
    dst[1] = a1 * inv;
}

// ---------------------------------------------------------------------------
// Workspace (floats): qb[32][4096] @0, knb[32*1024] @131072, vnb @163840,
// attn[32][4096] @196608, part[32*8*8*4*130] @327680  (~5.6 MB)
// ---------------------------------------------------------------------------
extern "C" void kernel_launch(void* const* d_in, const int* in_sizes, int n_in,
                              void* d_out, int out_size, void* d_ws, size_t ws_size,
                              hipStream_t stream)
{
    const float* x   = (const float*)d_in[0];
    const float* wq  = (const float*)d_in[1];
    const float* wk  = (const float*)d_in[2];
    const float* wv  = (const float*)d_in[3];
    const float* wo  = (const float*)d_in[4];
    const float* kc  = (const float*)d_in[5];
    const float* vc  = (const float*)d_in[6];
    const int* btab  = (const int*)d_in[8];
    const int* lens  = (const int*)d_in[10];

    float* qb   = (float*)d_ws;
    float* knb  = qb  + 32 * 4096;
    float* vnb  = knb + 32 * 1024;
    float* attn = vnb + 32 * 1024;
    float* part = attn + 32 * 4096;
    float* outp = (float*)d_out;

    hipMemsetAsync(d_ws, 0, (size_t)(32 * 4096 + 2 * 32 * 1024) * sizeof(float), stream);
    hipMemsetAsync(d_out, 0, (size_t)32 * 4096 * sizeof(float), stream);

    qkv_gemm<<<24 * 16, 256, 0, stream>>>(x, wq, wk, wv, qb, knb, vnb);
    rope_kernel<<<32 * 40, 64, 0, stream>>>(qb, knb, lens);
    attn_kernel<<<2048, 256, 0, stream>>>(kc, vc, qb, knb, vnb, btab, lens, part);
    combine_kernel<<<256, 256, 0, stream>>>(part, lens, attn);
    wo_gemm<<<16 * 16, 256, 0, stream>>>(attn, wo, outp);
}

// Round 4
// 191.704 us; speedup vs baseline: 1.5184x; 1.3289x over previous
//
#include <hip/hip_runtime.h>
#include <math.h>

// B=32, HID=4096, NH=32, NKV=8, HS=128, BS=16, MAXS=2048, groups=4

// ---------------------------------------------------------------------------
// Split-K f32 GEMM: out[b][n] += x[b][:] . w[n][:] over K-chunk of kcnt.
// BM=32, BN=256, BK=32. 256 threads, 32 accumulators/thread.
// ---------------------------------------------------------------------------
__device__ __forceinline__ void gemm_body(
    const float* __restrict__ x, const float* __restrict__ w,
    float* __restrict__ dst, int dstride, int kbase, int kcnt)
{
    __shared__ float xs[32][36];
    __shared__ float wsm[32][257];   // [k][n]
    int t = threadIdx.x;
    float acc[4][8];
#pragma unroll
    for (int i = 0; i < 4; ++i)
#pragma unroll
        for (int j = 0; j < 8; ++j) acc[i][j] = 0.f;

    int nsub = t & 31, bsub = t >> 5;

    for (int kt = 0; kt < kcnt; kt += 32) {
        int k0 = kbase + kt;
        {
            int b = t >> 3, k4 = (t & 7) << 2;
            float4 xv = *(const float4*)(x + (size_t)b * 4096 + k0 + k4);
            *(float4*)&xs[b][k4] = xv;
        }
        {
            int k4 = (t & 7) << 2;
            int nl0 = t >> 3;
#pragma unroll
            for (int i = 0; i < 8; ++i) {
                int nl = nl0 + (i << 5);
                float4 wv = *(const float4*)(w + (size_t)nl * 4096 + k0 + k4);
                wsm[k4 + 0][nl] = wv.x;
                wsm[k4 + 1][nl] = wv.y;
                wsm[k4 + 2][nl] = wv.z;
                wsm[k4 + 3][nl] = wv.w;
            }
        }
        __syncthreads();
#pragma unroll
        for (int k = 0; k < 32; ++k) {
            float xv[4], wv[8];
#pragma unroll
            for (int j = 0; j < 4; ++j) xv[j] = xs[bsub * 4 + j][k];
#pragma unroll
            for (int j = 0; j < 8; ++j) wv[j] = wsm[k][nsub + (j << 5)];
#pragma unroll
            for (int jb = 0; jb < 4; ++jb)
#pragma unroll
                for (int jn = 0; jn < 8; ++jn)
                    acc[jb][jn] = fmaf(xv[jb], wv[jn], acc[jb][jn]);
        }
        __syncthreads();
    }
#pragma unroll
    for (int jb = 0; jb < 4; ++jb) {
        int b = bsub * 4 + jb;
#pragma unroll
        for (int jn = 0; jn < 8; ++jn)
            atomicAdd(dst + (size_t)b * dstride + nsub + (jn << 5), acc[jb][jn]);
    }
}

// grid = 24 tiles * 16 splits
__global__ __launch_bounds__(256) void qkv_gemm(
    const float* __restrict__ x, const float* __restrict__ wq,
    const float* __restrict__ wk, const float* __restrict__ wv,
    float* __restrict__ qb, float* __restrict__ knb, float* __restrict__ vnb)
{
    int split = blockIdx.x & 15;
    int tile  = blockIdx.x >> 4;
    const float* w; float* dst; int dstride;
    if (tile < 16)      { w = wq + (size_t)tile * 256 * 4096;        dst = qb  + tile * 256;        dstride = 4096; }
    else if (tile < 20) { w = wk + (size_t)(tile - 16) * 256 * 4096; dst = knb + (tile - 16) * 256; dstride = 1024; }
    else                { w = wv + (size_t)(tile - 20) * 256 * 4096; dst = vnb + (tile - 20) * 256; dstride = 1024; }
    gemm_body(x, w, dst, dstride, split * 256, 256);
}

// grid = 16 tiles * 16 splits
__global__ __launch_bounds__(256) void wo_gemm(
    const float* __restrict__ attn, const float* __restrict__ wo,
    float* __restrict__ out)
{
    int split = blockIdx.x & 15;
    int tile  = blockIdx.x >> 4;
    gemm_body(attn, wo + (size_t)tile * 256 * 4096, out + tile * 256, 4096, split * 256, 256);
}

// ---------------------------------------------------------------------------
// RoPE in-place on q (32 heads) and k_new (8 heads). grid = 32*40, block = 64.
// ---------------------------------------------------------------------------
__global__ void rope_kernel(float* __restrict__ qb, float* __restrict__ knb,
                            const int* __restrict__ lens)
{
    int bid = blockIdx.x;
    int b = bid / 40, r = bid % 40;
    float* row = (r < 32) ? (qb + (size_t)b * 4096 + r * 128)
                          : (knb + (size_t)b * 1024 + (r - 32) * 128);
    int d = threadIdx.x;
    float pos = (float)(lens[b] - 1);
    float inv = exp2f(-(float)d * 0.207620505930460f);  // 10000^(-d/64)
    float fr = pos * inv;
    float s, c;
    sincosf(fr, &s, &c);
    float x1 = row[d], x2 = row[d + 64];
    row[d]      = x1 * c - x2 * s;
    row[d + 64] = x2 * c + x1 * s;
}

// ---------------------------------------------------------------------------
// Flash-decode attention. grid = 32*8*8 chunks of 256 positions, block = 256.
// Per 64-tile: A: prefetch V(t) (16 x float2, NAMED regs) and K(t+1)
// (8 x float4, NAMED regs); B: scores(t) from swizzled K-LDS (wave=group)
// covers the load latencies; C barrier; D: PV(t) pure-register FMA;
// E: commit K(t+1) to LDS; F barrier. Named scalars (not arrays!) so the
// allocator cannot demote to scratch (R2/R3 lesson: arrays -> 130MB scratch).
// ---------------------------------------------------------------------------
#define LOADK(tile_) { \
    int sl = ss[((tile_) << 6) + pr_row]; \
    const float* ksrc = (sl < 0) ? knew : (kc + (size_t)sl * 1024 + hoff); \
    ksrc += pr_q * 32; \
    k0 = *(const float4*)(ksrc);      k1 = *(const float4*)(ksrc + 4); \
    k2 = *(const float4*)(ksrc + 8);  k3 = *(const float4*)(ksrc + 12); \
    k4 = *(const float4*)(ksrc + 16); k5 = *(const float4*)(ksrc + 20); \
    k6 = *(const float4*)(ksrc + 24); k7 = *(const float4*)(ksrc + 28); }

#define COMMITK() { \
    *(float4*)&ks[pr_row][((q8 + 0) ^ r7) << 2] = k0; \
    *(float4*)&ks[pr_row][((q8 + 1) ^ r7) << 2] = k1; \
    *(float4*)&ks[pr_row][((q8 + 2) ^ r7) << 2] = k2; \
    *(float4*)&ks[pr_row][((q8 + 3) ^ r7) << 2] = k3; \
    *(float4*)&ks[pr_row][((q8 + 4) ^ r7) << 2] = k4; \
    *(float4*)&ks[pr_row][((q8 + 5) ^ r7) << 2] = k5; \
    *(float4*)&ks[pr_row][((q8 + 6) ^ r7) << 2] = k6; \
    *(float4*)&ks[pr_row][((q8 + 7) ^ r7) << 2] = k7; }

#define LOADV(i_) { \
    int sl = ss[ibase + i_]; \
    const float* vsrc = (sl < 0) ? vnew : (vc + (size_t)sl * 1024 + hoff); \
    v##i_ = *(const float2*)(vsrc + d0); }

#define PVQ(i_, A0, A1, A2, A3) { \
    float4 w0 = *(const float4*)&ps[0][rp0 + i_]; \
    float4 w1 = *(const float4*)&ps[1][rp0 + i_]; \
    float4 w2 = *(const float4*)&ps[2][rp0 + i_]; \
    float4 w3 = *(const float4*)&ps[3][rp0 + i_]; \
    o00 = fmaf(w0.x, A0.x, o00); o01 = fmaf(w0.x, A0.y, o01); \
    o00 = fmaf(w0.y, A1.x, o00); o01 = fmaf(w0.y, A1.y, o01); \
    o00 = fmaf(w0.z, A2.x, o00); o01 = fmaf(w0.z, A2.y, o01); \
    o00 = fmaf(w0.w, A3.x, o00); o01 = fmaf(w0.w, A3.y, o01); \
    o10 = fmaf(w1.x, A0.x, o10); o11 = fmaf(w1.x, A0.y, o11); \
    o10 = fmaf(w1.y, A1.x, o10); o11 = fmaf(w1.y, A1.y, o11); \
    o10 = fmaf(w1.z, A2.x, o10); o11 = fmaf(w1.z, A2.y, o11); \
    o10 = fmaf(w1.w, A3.x, o10); o11 = fmaf(w1.w, A3.y, o11); \
    o20 = fmaf(w2.x, A0.x, o20); o21 = fmaf(w2.x, A0.y, o21); \
    o20 = fmaf(w2.y, A1.x, o20); o21 = fmaf(w2.y, A1.y, o21); \
    o20 = fmaf(w2.z, A2.x, o20); o21 = fmaf(w2.z, A2.y, o21); \
    o20 = fmaf(w2.w, A3.x, o20); o21 = fmaf(w2.w, A3.y, o21); \
    o30 = fmaf(w3.x, A0.x, o30); o31 = fmaf(w3.x, A0.y, o31); \
    o30 = fmaf(w3.y, A1.x, o30); o31 = fmaf(w3.y, A1.y, o31); \
    o30 = fmaf(w3.z, A2.x, o30); o31 = fmaf(w3.z, A2.y, o31); \
    o30 = fmaf(w3.w, A3.x, o30); o31 = fmaf(w3.w, A3.y, o31); }

__global__ __launch_bounds__(256, 1) void attn_kernel(
    const float* __restrict__ kc, const float* __restrict__ vc,
    const float* __restrict__ qb, const float* __restrict__ knb,
    const float* __restrict__ vnb,
    const int* __restrict__ btab, const int* __restrict__ lens,
    float* __restrict__ part)
{
    int bid = blockIdx.x;
    int c = bid & 7, h = (bid >> 3) & 7, b = bid >> 6;
    int len = lens[b];
    int p0 = c << 8;
    if (p0 >= len) return;
    int pend = min(len - p0, 256);
    int nt = (pend + 63) >> 6;
    int last = len - 1;

    __shared__ float ks[64][128];   // 32 KB, f4-col XOR-swizzled
    __shared__ float qs[4][128];
    __shared__ float ps[4][64];
    __shared__ int   ss[256];       // slot table; -1 => new k/v row
    __shared__ float corrs[4];

    int t = threadIdx.x;
    int wave = t >> 6, lane = t & 63;
    int hoff = h * 128;

    {   // slot table for the whole chunk
        int p = p0 + t;
        ss[t] = (p == last) ? -1 : (btab[b * 128 + (p >> 4)] * 16 + (p & 15));
    }
    if (t < 128) {
        int g = t >> 5, d4 = (t & 31) << 2;
        *(float4*)&qs[g][d4] =
            *(const float4*)(qb + (size_t)b * 4096 + (size_t)(h * 4 + g) * 128 + d4);
    }
    __syncthreads();

    int pr_row = t >> 2;          // 0..63
    int pr_q   = t & 3;           // 128B quarter of the row
    int q8 = pr_q << 3;
    int r7 = pr_row & 7;
    const float* knew = knb + ((size_t)b * 8 + h) * 128;
    const float* vnew = vnb + ((size_t)b * 8 + h) * 128;

    float4 k0, k1, k2, k3, k4, k5, k6, k7;
    LOADK(0)
    COMMITK()
    __syncthreads();

    float m = -INFINITY, lsum = 0.f;
    float o00 = 0.f, o01 = 0.f, o10 = 0.f, o11 = 0.f;
    float o20 = 0.f, o21 = 0.f, o30 = 0.f, o31 = 0.f;

    const float scale = 0.08838834764831845f;
    int xm = lane & 7;
    int d0 = lane << 1;
    int rp0 = wave << 4;

    for (int tt = 0; tt < nt; ++tt) {
        int tlen = min(pend - (tt << 6), 64);
        // ---- A1: prefetch V(t) rows rp0..rp0+15 into named regs ----
        float2 v0, v1, v2, v3, v4, v5, v6, v7;
        float2 v8, v9, v10, v11, v12, v13, v14, v15;
        {
            int ibase = (tt << 6) + rp0;
            LOADV(0)  LOADV(1)  LOADV(2)  LOADV(3)
            LOADV(4)  LOADV(5)  LOADV(6)  LOADV(7)
            LOADV(8)  LOADV(9)  LOADV(10) LOADV(11)
            LOADV(12) LOADV(13) LOADV(14) LOADV(15)
        }
        // ---- A2: prefetch K(t+1) into named regs ----
        if (tt + 1 < nt) LOADK(tt + 1)
        // ---- B: scores(t), wave = GQA group ----
        {
            float ax = 0.f, ay = 0.f, az = 0.f, aw = 0.f;
#pragma unroll
            for (int cc = 0; cc < 32; ++cc) {
                float4 kv = *(float4*)&ks[lane][(cc ^ xm) << 2];
                float4 qv = *(const float4*)&qs[wave][cc << 2];
                ax = fmaf(kv.x, qv.x, ax);
                ay = fmaf(kv.y, qv.y, ay);
                az = fmaf(kv.z, qv.z, az);
                aw = fmaf(kv.w, qv.w, aw);
            }
            float s = (lane < tlen) ? (ax + ay + az + aw) * scale : -INFINITY;
            float smax = s;
#pragma unroll
            for (int off = 32; off; off >>= 1) smax = fmaxf(smax, __shfl_xor(smax, off, 64));
            float mnew = fmaxf(m, smax);
            float corr = __expf(m - mnew);
            float pexp = (lane < tlen) ? __expf(s - mnew) : 0.f;
            float psum = pexp;
#pragma unroll
            for (int off = 32; off; off >>= 1) psum += __shfl_xor(psum, off, 64);
            lsum = lsum * corr + psum;
            m = mnew;
            ps[wave][lane] = pexp;
            if (lane == 0) corrs[wave] = corr;
        }
        __syncthreads();   // C
        // ---- D: PV(t) from registers; wave covers rows rp0..rp0+15, all 4 g ----
        {
            float c0 = corrs[0], c1 = corrs[1], c2 = corrs[2], c3 = corrs[3];
            o00 *= c0; o01 *= c0; o10 *= c1; o11 *= c1;
            o20 *= c2; o21 *= c2; o30 *= c3; o31 *= c3;
            PVQ(0,  v0,  v1,  v2,  v3)
            PVQ(4,  v4,  v5,  v6,  v7)
            PVQ(8,  v8,  v9,  v10, v11)
            PVQ(12, v12, v13, v14, v15)
        }
        // ---- E: commit prefetched K(t+1) to LDS (swizzled) ----
        if (tt + 1 < nt) COMMITK()
        __syncthreads();   // F
    }

    // epilogue: cross-wave O reduction (overlay scratch on ks)
    float* oacc = (float*)ks;   // [wave][g][128]
    oacc[(wave * 4 + 0) * 128 + d0]     = o00;
    oacc[(wave * 4 + 0) * 128 + d0 + 1] = o01;
    oacc[(wave * 4 + 1) * 128 + d0]     = o10;
    oacc[(wave * 4 + 1) * 128 + d0 + 1] = o11;
    oacc[(wave * 4 + 2) * 128 + d0]     = o20;
    oacc[(wave * 4 + 2) * 128 + d0 + 1] = o21;
    oacc[(wave * 4 + 3) * 128 + d0]     = o30;
    oacc[(wave * 4 + 3) * 128 + d0 + 1] = o31;
    float* pgbase = part + (size_t)(((b * 8 + h) * 8 + c) * 4) * 130;
    if (lane == 0) { pgbase[wave * 130] = m; pgbase[wave * 130 + 1] = lsum; }
    __syncthreads();
    for (int e = t; e < 512; e += 256) {
        int g = e >> 7, d = e & 127;
        float v = oacc[(0 + g) * 128 + d] + oacc[(4 + g) * 128 + d]
                + oacc[(8 + g) * 128 + d] + oacc[(12 + g) * 128 + d];
        pgbase[g * 130 + 2 + d] = v;
    }
}

// grid = 256 (b*8+h), block = 256 (4 groups x 64 lanes)
__global__ __launch_bounds__(256) void combine_kernel(
    const float* __restrict__ part, const int* __restrict__ lens,
    float* __restrict__ attn)
{
    int b = blockIdx.x >> 3, h = blockIdx.x & 7;
    int t = threadIdx.x;
    int g = t >> 6, lane = t & 63;
    int len = lens[b];
    int nch = (len + 255) >> 8;
    size_t base = ((size_t)(b * 8 + h) * 32 + g) * 130;
    float M = -INFINITY;
    for (int cc = 0; cc < nch; ++cc)
        M = fmaxf(M, part[base + (size_t)cc * 520]);
    float denom = 0.f, a0 = 0.f, a1 = 0.f;
    for (int cc = 0; cc < nch; ++cc) {
        const float* pg = part + base + (size_t)cc * 520;
        float w = __expf(pg[0] - M);
        denom += w * pg[1];
        a0 += w * pg[2 + (lane << 1)];
        a1 += w * pg[3 + (lane << 1)];
    }
    float inv = 1.f / denom;
    float* dst = attn + (size_t)b * 4096 + (size_t)(h * 4 + g) * 128 + (lane << 1);
    dst[0] = a0 * inv;
    dst[1] = a1 * inv;
}

// ---------------------------------------------------------------------------
// Workspace (floats): qb[32][4096] @0, knb[32*1024] @131072, vnb @163840,
// attn[32][4096] @196608, part[32*8*8*4*130] @327680  (~5.6 MB)
// ---------------------------------------------------------------------------
extern "C" void kernel_launch(void* const* d_in, const int* in_sizes, int n_in,
                              void* d_out, int out_size, void* d_ws, size_t ws_size,
                              hipStream_t stream)
{
    const float* x   = (const float*)d_in[0];
    const float* wq  = (const float*)d_in[1];
    const float* wk  = (const float*)d_in[2];
    const float* wv  = (const float*)d_in[3];
    const float* wo  = (const float*)d_in[4];
    const float* kc  = (const float*)d_in[5];
    const float* vc  = (const float*)d_in[6];
    const int* btab  = (const int*)d_in[8];
    const int* lens  = (const int*)d_in[10];

    float* qb   = (float*)d_ws;
    float* knb  = qb  + 32 * 4096;
    float* vnb  = knb + 32 * 1024;
    float* attn = vnb + 32 * 1024;
    float* part = attn + 32 * 4096;
    float* outp = (float*)d_out;

    hipMemsetAsync(d_ws, 0, (size_t)(32 * 4096 + 2 * 32 * 1024) * sizeof(float), stream);
    hipMemsetAsync(d_out, 0, (size_t)32 * 4096 * sizeof(float), stream);

    qkv_gemm<<<24 * 16, 256, 0, stream>>>(x, wq, wk, wv, qb, knb, vnb);
    rope_kernel<<<32 * 40, 64, 0, stream>>>(qb, knb, lens);
    attn_kernel<<<2048, 256, 0, stream>>>(kc, vc, qb, knb, vnb, btab, lens, part);
    combine_kernel<<<256, 256, 0, stream>>>(part, lens, attn);
    wo_gemm<<<16 * 16, 256, 0, stream>>>(attn, wo, outp);
}